// Round 14
// baseline (137.596 us; speedup 1.0000x reference)
//
#include <hip/hip_runtime.h>
#include <hip/hip_bf16.h>
#include <math.h>

// KAN layer: out = GELU( einsum('bik,ikj->bj', basis, W) + bias ),
//   basis[b,i,k] = x[b,i]^k, B=4096, D=1024, K=5, U=1024.
//
// Round 15: attack the measured constraint (LDS traffic + issue slots per
// MFMA; no pipe saturated) by raising arithmetic intensity, not occupancy:
// tile 128x128, 8 waves (512 thr), grid 256 = 1 block/CU. Per k-iter:
// staged bytes 10->12 KB but MFMAs 32->64 (LDS bytes/MFMA 1.88->0.69 KB);
// per-CU barrier events halve; waves/SIMD stays 2 (r12 proved more waves
// don't help here). Risk containment: ledger counts are r12's
// HARNESS-PROVEN pair (class X: 2 loads/stage, WAITBAR(4), tail 4/4/2/0;
// class Y: 1 load/stage, WAITBAR(2), tail 2/2/1/0; ring-4, distance-3),
// and the x-gather / XOR-swizzle / read-formula / PACKA are r10's proven
// fragments -- only geometry scales (the swizzle term (m>>2)&1 is
// invariant under the new row split). Prep unchanged from r10.

#define B_DIM 4096
#define D_DIM 1024
#define U_DIM 1024
#define NKB 128             // 32-wide k-blocks

typedef unsigned short ushort_t;
typedef __attribute__((ext_vector_type(8))) short bf16x8;   // MFMA A/B frag
typedef __attribute__((ext_vector_type(4))) float f32x4;    // MFMA C/D frag
typedef __attribute__((ext_vector_type(2))) float f32x2;

__device__ __forceinline__ ushort_t f2bf(float f) {
  union { float f; unsigned int u; } v;
  v.f = f;
  unsigned int r = v.u + 0x7FFFu + ((v.u >> 16) & 1u);
  return (ushort_t)(r >> 16);
}

__device__ __forceinline__ void load_lds16(const ushort_t* g, ushort_t* l) {
  __builtin_amdgcn_global_load_lds(
      (const __attribute__((address_space(1))) ushort_t*)g,
      (__attribute__((address_space(3))) ushort_t*)l, 16, 0, 0);
}

__device__ __forceinline__ float gelu_exact(float v) {
  return 0.5f * v * (1.0f + erff(v * 0.70710678118654752f));
}

// ---------------- prep 1: W -> B_packed (planes 1..4) + fold k=0 partials ----------------
__global__ __launch_bounds__(256) void w_pack_kernel(
    const float* __restrict__ W, ushort_t* __restrict__ Bp,
    float* __restrict__ fold32) {
  __shared__ float red[64];
  const int bidx = blockIdx.x;          // 0..2047
  const int n16  = bidx >> 5;           // 0..63
  const int kq   = bidx & 31;           // 0..31
  const int wave = threadIdx.x >> 6;
  const int lane = threadIdx.x & 63;
  const int m    = lane & 15;
  const int ko   = lane >> 4;
  const int j    = n16 * 16 + m;
  const int kblk = kq * 4 + wave;       // 0..127
  const int i0   = kblk * 8 + ko * 2;

  ushort_t o[8];
  float s0 = 0.0f;
#pragma unroll
  for (int t2 = 0; t2 < 2; ++t2) {
    const int i = i0 + t2;
    s0 += W[(size_t)(i * 5) * U_DIM + j];       // k=0 plane (ones basis)
#pragma unroll
    for (int e = 0; e < 4; ++e)
      o[t2 * 4 + e] = f2bf(W[(size_t)(i * 5 + e + 1) * U_DIM + j]);
  }
  *(uint4*)(Bp + ((size_t)n16 * NKB + kblk) * 512 + lane * 8) = *(const uint4*)o;

  s0 += __shfl_xor(s0, 16, 64);
  s0 += __shfl_xor(s0, 32, 64);
  if (ko == 0) red[wave * 16 + m] = s0;
  __syncthreads();
  if (wave == 0 && ko == 0)
    fold32[(size_t)j * 32 + kq] =
        red[m] + red[16 + m] + red[32 + m] + red[48 + m];
}

// ---------------- prep 2: collapse fold32 -> b2 = bias + fold ----------------
__global__ __launch_bounds__(256) void fold_final_kernel(
    const float* __restrict__ fold32, const float* __restrict__ bias,
    float* __restrict__ b2) {
  const int j = blockIdx.x * 256 + threadIdx.x;   // grid.x = 4
  const float4* fp = (const float4*)(fold32 + (size_t)j * 32);
  float s = bias[j];
#pragma unroll
  for (int g = 0; g < 8; ++g) {
    const float4 f = fp[g];
    s += f.x + f.y + f.z + f.w;
  }
  b2[j] = s;
}

// ---------------- main GEMM: 128x128 tile, 8 waves, BK=32, ring-4 counted-vmcnt ----------------
// Buffer (ushorts, 6144 = 12 KB): [0..2047] = x fp32, 128 rows x 32 B
//   (row r at byte r*32; 16B chunk c holds i-quad c ^ ((r>>2)&1));
// [2048..6143] = 8 Bp units (1 KB each). x4 buffers = 48 KB -> 1 block/CU.
// Staging: wave w stages B unit w; waves 0-3 also stage x rows w*32..+31.
// Class X (waves 0-3): 2 loads/iter, WAITBAR(4), tail 4/4/2/0 (r12-proven).
// Class Y (waves 4-7): 1 load/iter, WAITBAR(2), tail 2/2/1/0 (r12-proven).
// Wave (wm=w>>2, wn=w&3) owns a 64x32 output: acc[4][2].
__global__ __launch_bounds__(512) void gemm_kernel(
    const float* __restrict__ x, const ushort_t* __restrict__ Bp,
    const float* __restrict__ b2, float* __restrict__ C) {
  __shared__ __align__(16) ushort_t lds[4][6144];   // 4 x 12 KB

  const int tid  = threadIdx.x;
  const int wave = tid >> 6;              // 0..7
  const int lane = tid & 63;
  const int wm   = wave >> 2;             // 0..1 : 64-row half
  const int wn   = wave & 3;              // 0..3 : 32-col quarter
  const int m    = lane & 15;
  const int ko   = lane >> 4;

  // XCD swizzle (bijective, 256 = 8 xcd * 32): each XCD owns a 4m x 8n
  // chunk (32 blocks on its 32 CUs); its x slice (4 x 128 rows = 2 MB)
  // is L2-resident.
  const int lin  = blockIdx.y * 8 + blockIdx.x;
  const int xcd  = lin & 7;
  const int slot = lin >> 3;              // 0..31
  const int mt   = xcd * 4 + (slot & 3);  // 0..31
  const int nt   = slot >> 2;             // 0..7
  const int n16b = nt * 8;

  // x gather (waves 0-3 only): lane l -> block-local row r = wave*32+(l>>1),
  // 16B chunk c = l&1, source chunk pre-swizzled: c ^ ((r>>2)&1)
  // = c ^ ((l>>3)&1)  (wave*32 contributes an even multiple of 8 to r>>2).
  const int xrow  = (wave & 3) * 32 + (lane >> 1);
  const int xchk  = (lane & 1) ^ ((lane >> 3) & 1);
  const ushort_t* gx =
      (const ushort_t*)(x + ((size_t)(mt * 128 + xrow)) * D_DIM + xchk * 4);
  const int ldx = (wave & 3) * 512 + lane * 8;      // ushort idx (16B/lane)

  // B staging: wave w stages unit n16b + w (dense 1 KB bursts)
  const ushort_t* gb = Bp + ((size_t)(n16b + wave) * NKB) * 512 + lane * 8;
  const int ldb = 2048 + wave * 512 + lane * 8;

  // x read (lane-const byte offset): row = wm*64 + mf*16 + m, wants global
  // i-pair ko -> chunk (ko>>1)^((m>>2)&1) (wm*64, mf*16 don't touch that
  // bit), pair (ko&1). mf adds 512 B; wm adds 2048 B.
  const int xoff = wm * 2048 + m * 32 +
                   ((((ko >> 1) ^ ((m >> 2) & 1))) << 4) + (ko & 1) * 8;

  f32x4 acc[4][2];
  const f32x4 zero = {0.0f, 0.0f, 0.0f, 0.0f};
#pragma unroll
  for (int mf = 0; mf < 4; ++mf)
#pragma unroll
    for (int nf = 0; nf < 2; ++nf) acc[mf][nf] = zero;

#define WAITBAR(N) \
  asm volatile("s_waitcnt vmcnt(" #N ")\n\ts_barrier" ::: "memory")

// class X (waves 0-3): x rows + 1 B unit at literal unit offset REL
#define STAGE_X(bb, rel)                                                \
  do {                                                                  \
    load_lds16(gx + (rel) * 16,  &lds[bb][ldx]);                        \
    load_lds16(gb + (rel) * 512, &lds[bb][ldb]);                        \
  } while (0)

// class Y (waves 4-7): 1 B unit only
#define STAGE_Y(bb, rel)                                                \
  do {                                                                  \
    load_lds16(gb + (rel) * 512, &lds[bb][ldb]);                        \
  } while (0)

// powers + pack: v_cvt_pk_bf16_f32 (RNE, same rounding as f2bf)
#define PACKA(dst, xp)                                                  \
  do {                                                                  \
    const f32x2 p1 = (xp);                                              \
    const f32x2 p2 = p1 * p1;                                           \
    const f32x2 p3 = p2 * p1;                                           \
    const f32x2 p4 = p2 * p2;                                           \
    union { bf16x8 v; unsigned int u[4]; } r_;                          \
    asm("v_cvt_pk_bf16_f32 %0, %1, %2" : "=v"(r_.u[0]) : "v"(p1[0]), "v"(p2[0])); \
    asm("v_cvt_pk_bf16_f32 %0, %1, %2" : "=v"(r_.u[1]) : "v"(p3[0]), "v"(p4[0])); \
    asm("v_cvt_pk_bf16_f32 %0, %1, %2" : "=v"(r_.u[2]) : "v"(p1[1]), "v"(p2[1])); \
    asm("v_cvt_pk_bf16_f32 %0, %1, %2" : "=v"(r_.u[3]) : "v"(p3[1]), "v"(p4[1])); \
    dst = r_.v;                                                         \
  } while (0)

#define COMPUTE(bb)                                                     \
  do {                                                                  \
    const char* xu = (const char*)&lds[bb][0];                          \
    bf16x8 a[4], b[2];                                                  \
    _Pragma("unroll")                                                   \
    for (int mf = 0; mf < 4; ++mf) {                                    \
      const f32x2 q = *(const f32x2*)(xu + xoff + mf * 512);            \
      PACKA(a[mf], q);                                                  \
    }                                                                   \
    _Pragma("unroll")                                                   \
    for (int nf = 0; nf < 2; ++nf)                                      \
      b[nf] = *(const bf16x8*)&lds[bb][2048 + (wn * 2 + nf) * 512 + lane * 8]; \
    _Pragma("unroll")                                                   \
    for (int mf = 0; mf < 4; ++mf)                                      \
      _Pragma("unroll")                                                 \
      for (int nf = 0; nf < 2; ++nf)                                    \
        acc[mf][nf] = __builtin_amdgcn_mfma_f32_16x16x32_bf16(          \
            a[mf], b[nf], acc[mf][nf], 0, 0, 0);                        \
  } while (0)

  if (wave < 4) {
    // ---- class X: 2 loads/stage; prologue 6 in flight; WAITBAR(4) ----
    STAGE_X(0, 0);
    STAGE_X(1, 1);
    STAGE_X(2, 2);
    gx += 4 * 16;                         // rebase: rel 0 == k-block 4
    gb += 4 * 512;
    for (int base = 0; base < 124; base += 4) {
      WAITBAR(4); STAGE_X(3, -1); COMPUTE(0);   // stage base+3
      WAITBAR(4); STAGE_X(0,  0); COMPUTE(1);   // stage base+4
      WAITBAR(4); STAGE_X(1,  1); COMPUTE(2);   // stage base+5
      WAITBAR(4); STAGE_X(2,  2); COMPUTE(3);   // stage base+6
      gx += 4 * 16;
      gb += 4 * 512;
    }
    WAITBAR(4); STAGE_X(3, -1); COMPUTE(0);     // it=124, stage 127
    WAITBAR(4); COMPUTE(1);                     // it=125
    WAITBAR(2); COMPUTE(2);                     // it=126
    WAITBAR(0); COMPUTE(3);                     // it=127
  } else {
    // ---- class Y: 1 load/stage; prologue 3 in flight; WAITBAR(2) ----
    STAGE_Y(0, 0);
    STAGE_Y(1, 1);
    STAGE_Y(2, 2);
    gb += 4 * 512;
    for (int base = 0; base < 124; base += 4) {
      WAITBAR(2); STAGE_Y(3, -1); COMPUTE(0);
      WAITBAR(2); STAGE_Y(0,  0); COMPUTE(1);
      WAITBAR(2); STAGE_Y(1,  1); COMPUTE(2);
      WAITBAR(2); STAGE_Y(2,  2); COMPUTE(3);
      gb += 4 * 512;
    }
    WAITBAR(2); STAGE_Y(3, -1); COMPUTE(0);     // it=124, stage 127
    WAITBAR(2); COMPUTE(1);                     // it=125
    WAITBAR(1); COMPUTE(2);                     // it=126
    WAITBAR(0); COMPUTE(3);                     // it=127
  }
#undef STAGE_X
#undef STAGE_Y
#undef COMPUTE
#undef PACKA
#undef WAITBAR

  // epilogue: C/D map: col = lane&15, row = (lane>>4)*4 + reg
  const int crow0 = mt * 128 + wm * 64 + (lane >> 4) * 4;
  const int ccol0 = nt * 128 + wn * 32 + m;
#pragma unroll
  for (int nf = 0; nf < 2; ++nf) {
    const int col = ccol0 + nf * 16;
    const float bv = b2[col];
#pragma unroll
    for (int mf = 0; mf < 4; ++mf) {
#pragma unroll
      for (int r = 0; r < 4; ++r) {
        const int row = crow0 + mf * 16 + r;
        C[(size_t)row * U_DIM + col] = gelu_exact(acc[mf][nf][r] + bv);
      }
    }
  }
}

// ---------------- fallback (ws too small): fp32, no workspace ----------------
__global__ void fallback_kernel(const float* __restrict__ x, const float* __restrict__ W,
                                const float* __restrict__ bias, float* __restrict__ out) {
  int j  = blockIdx.x * 256 + threadIdx.x;
  int b0 = blockIdx.y * 16;
  float acc[16];
#pragma unroll
  for (int t = 0; t < 16; ++t) acc[t] = 0.0f;
  for (int i = 0; i < D_DIM; ++i) {
    const float* wr = W + (size_t)i * 5 * U_DIM + j;
    float w0 = wr[0 * U_DIM], w1 = wr[1 * U_DIM], w2 = wr[2 * U_DIM];
    float w3 = wr[3 * U_DIM], w4 = wr[4 * U_DIM];
#pragma unroll
    for (int t = 0; t < 16; ++t) {
      float xv = x[(size_t)(b0 + t) * D_DIM + i];
      float x2 = xv * xv;
      acc[t] += w0 + xv * w1 + x2 * w2 + x2 * xv * w3 + x2 * x2 * w4;
    }
  }
  float bv = bias[j];
#pragma unroll
  for (int t = 0; t < 16; ++t)
    out[(size_t)(b0 + t) * U_DIM + j] = gelu_exact(acc[t] + bv);
}

extern "C" void kernel_launch(void* const* d_in, const int* in_sizes, int n_in,
                              void* d_out, int out_size, void* d_ws, size_t ws_size,
                              hipStream_t stream) {
  const float* x    = (const float*)d_in[0];   // (4096, 1024)
  const float* W    = (const float*)d_in[1];   // (1024, 5, 1024), row r = i*5+k
  const float* bias = (const float*)d_in[2];   // (1024,)
  float* out = (float*)d_out;                  // (4096, 1024) fp32

  const size_t szB = (size_t)U_DIM * 4096 * sizeof(ushort_t);    // 8.39 MB
  const size_t szF = (size_t)32 * U_DIM * sizeof(float);         //  128 KB
  const size_t szb = (size_t)U_DIM * sizeof(float);              //    4 KB

  if (ws_size >= szB + szF + szb) {
    ushort_t* Bp   = (ushort_t*)d_ws;
    float*    f32p = (float*)((char*)d_ws + szB);
    float*    b2   = (float*)((char*)d_ws + szB + szF);
    w_pack_kernel<<<dim3(2048), 256, 0, stream>>>(W, Bp, f32p);
    fold_final_kernel<<<dim3(U_DIM / 256), 256, 0, stream>>>(f32p, bias, b2);
    gemm_kernel<<<dim3(U_DIM / 128, B_DIM / 128), 512, 0, stream>>>(x, Bp, b2, out);
  } else {
    fallback_kernel<<<dim3(U_DIM / 256, B_DIM / 16), 256, 0, stream>>>(x, W, bias, out);
  }
}

// Round 15
// 130.206 us; speedup vs baseline: 1.0568x; 1.0568x over previous
//
#include <hip/hip_runtime.h>
#include <hip/hip_bf16.h>
#include <math.h>

// KAN layer: out = GELU( einsum('bik,ikj->bj', basis, W) + bias ),
//   basis[b,i,k] = x[b,i]^k, B=4096, D=1024, K=5, U=1024.
//
// FINAL (round 15): the round-10 kernel bit-for-bit -- the empirically
// best configuration, reproduced twice (131.1 / 130.6 us total; gemm
// 55.5 us timed-graph). The structure family is probed on every axis:
//  - BK64 staging granule (r7): raced (tripwire).
//  - 64x64 tile, 4 blocks/CU (r12): gemm 55.5->68 us. More waves SHARE the
//    per-CU LDS/issue budget; halving tile halves MFMA-per-barrier.
//  - 128x128 tile, 8 waves (r14): gemm 55.5->65.5 us, conflicts 2.1M->4.2M.
//    Cutting LDS bytes/MFMA 2.7x did NOT help => constraint is the serial
//    per-iter chain (barrier -> vmcnt -> x-read -> PACKA -> MFMA) at
//    2 waves/SIMD, invariant to tile geometry.
// r10 = 64x128 tile, wave-class-split staging (waves 0-1: x-half + 2 B
// units, WAITBAR(6); waves 2-3: 2 B units, WAITBAR(4)), ring-4
// counted-vmcnt, distance 3, in-register A-build from raw x (PACKA via
// v_cvt_pk_bf16_f32), XOR-swizzled x tile, XCD-bijective block swizzle,
// w_pack@2048 + fold collapse prep. Dispatches: 3. Workspace 8.5 MB.
// Residual ~64 us is fixed harness reset cost (established by r1-r9
// workspace-size bracketing), outside kernel control.

#define B_DIM 4096
#define D_DIM 1024
#define U_DIM 1024
#define NKB 128             // 32-wide k-blocks

typedef unsigned short ushort_t;
typedef __attribute__((ext_vector_type(8))) short bf16x8;   // MFMA A/B frag
typedef __attribute__((ext_vector_type(4))) float f32x4;    // MFMA C/D frag
typedef __attribute__((ext_vector_type(2))) float f32x2;

__device__ __forceinline__ ushort_t f2bf(float f) {
  union { float f; unsigned int u; } v;
  v.f = f;
  unsigned int r = v.u + 0x7FFFu + ((v.u >> 16) & 1u);
  return (ushort_t)(r >> 16);
}

__device__ __forceinline__ void load_lds16(const ushort_t* g, ushort_t* l) {
  __builtin_amdgcn_global_load_lds(
      (const __attribute__((address_space(1))) ushort_t*)g,
      (__attribute__((address_space(3))) ushort_t*)l, 16, 0, 0);
}

__device__ __forceinline__ float gelu_exact(float v) {
  return 0.5f * v * (1.0f + erff(v * 0.70710678118654752f));
}

// ---------------- prep 1: W -> B_packed (planes 1..4) + fold k=0 partials ----------------
// 2048 blocks (8/CU): block (n16, kq) packs 4 kblks (one per wave; one
// uint4 store per thread) and writes fold32[j*32 + kq] = sum over
// i in kq*32..+31 of W[i,0,j]. Every fold32 slot written exactly once.
__global__ __launch_bounds__(256) void w_pack_kernel(
    const float* __restrict__ W, ushort_t* __restrict__ Bp,
    float* __restrict__ fold32) {
  __shared__ float red[64];
  const int bidx = blockIdx.x;          // 0..2047
  const int n16  = bidx >> 5;           // 0..63
  const int kq   = bidx & 31;           // 0..31
  const int wave = threadIdx.x >> 6;
  const int lane = threadIdx.x & 63;
  const int m    = lane & 15;
  const int ko   = lane >> 4;
  const int j    = n16 * 16 + m;
  const int kblk = kq * 4 + wave;       // 0..127
  const int i0   = kblk * 8 + ko * 2;

  ushort_t o[8];
  float s0 = 0.0f;
#pragma unroll
  for (int t2 = 0; t2 < 2; ++t2) {
    const int i = i0 + t2;
    s0 += W[(size_t)(i * 5) * U_DIM + j];       // k=0 plane (ones basis)
#pragma unroll
    for (int e = 0; e < 4; ++e)
      o[t2 * 4 + e] = f2bf(W[(size_t)(i * 5 + e + 1) * U_DIM + j]);
  }
  *(uint4*)(Bp + ((size_t)n16 * NKB + kblk) * 512 + lane * 8) = *(const uint4*)o;

  // reduce k=0 partial over ko groups, then across the 4 waves via LDS
  s0 += __shfl_xor(s0, 16, 64);
  s0 += __shfl_xor(s0, 32, 64);
  if (ko == 0) red[wave * 16 + m] = s0;
  __syncthreads();
  if (wave == 0 && ko == 0)
    fold32[(size_t)j * 32 + kq] =
        red[m] + red[16 + m] + red[32 + m] + red[48 + m];
}

// ---------------- prep 2: collapse fold32 -> b2 = bias + fold ----------------
__global__ __launch_bounds__(256) void fold_final_kernel(
    const float* __restrict__ fold32, const float* __restrict__ bias,
    float* __restrict__ b2) {
  const int j = blockIdx.x * 256 + threadIdx.x;   // grid.x = 4
  const float4* fp = (const float4*)(fold32 + (size_t)j * 32);
  float s = bias[j];
#pragma unroll
  for (int g = 0; g < 8; ++g) {
    const float4 f = fp[g];
    s += f.x + f.y + f.z + f.w;
  }
  b2[j] = s;
}

// ---------------- main GEMM: 64x128 tile, BK=32, 4-buf counted-vmcnt, x4 unroll ----------------
// Buffer (ushorts): [0..1023] = x fp32 (64 rows x 32 B; 16B chunk t of row r
// holds global i-quad t ^ ((r>>2)&1) -- the XOR swizzle), [1024..5119] =
// 8 Bp units. 10 KB x 4 = 40 KB. Wave-class staging:
//   waves 0-1: x-half(wave) + B units {wave, wave+4}  -> 3 loads/iter,
//              ledger = proven loop (WAITBAR 6/6/3/0).
//   waves 2-3: B units {wave, wave+4} only            -> 2 loads/iter,
//              same 2-stages-in-flight rule (WAITBAR 4/4/2/0).
// x is staged exactly once per half (no duplicate gathers).
__global__ __launch_bounds__(256) void gemm_kernel(
    const float* __restrict__ x, const ushort_t* __restrict__ Bp,
    const float* __restrict__ b2, float* __restrict__ C) {
  __shared__ __align__(16) ushort_t lds[4][5120];   // 4 x 10 KB

  const int tid  = threadIdx.x;
  const int wave = tid >> 6;
  const int lane = tid & 63;
  const int wm   = wave >> 1;             // 0..1 : 32-row half
  const int wn   = wave & 1;              // 0..1 : 64-col half
  const int m    = lane & 15;
  const int ko   = lane >> 4;

  // XCD swizzle (bijective, 512 = 8 xcd * 64): each XCD owns an 8m x 8n
  // chunk co-resident on its 32 CUs; its x slice (2 MB) is L2-resident.
  const int lin  = blockIdx.y * 8 + blockIdx.x;
  const int xcd  = lin & 7;
  const int slot = lin >> 3;              // 0..63
  const int mt   = xcd * 8 + (slot & 7);  // 0..63
  const int nt   = slot >> 3;             // 0..7
  const int m16b = mt * 4;
  const int n16b = nt * 8;

  // x gather (waves 0,1 only): lane l -> block-local row r = wave*32+(l>>1),
  // 16B chunk c = l&1, source chunk pre-swizzled: c ^ ((r>>2)&1)
  // = c ^ ((l>>3)&1).
  const int xrow  = (wave & 1) * 32 + (lane >> 1);
  const int xchk  = (lane & 1) ^ ((lane >> 3) & 1);
  const ushort_t* gx =
      (const ushort_t*)(x + ((size_t)(m16b * 16 + xrow)) * D_DIM + xchk * 4);
  const int ldx = (wave & 1) * 512 + lane * 8;      // ushort idx (16B/lane)

  // B staging: wave w stages units w and 4+w (dense 1 KB bursts)
  const ushort_t* gb0 = Bp + ((size_t)(n16b + wave) * NKB) * 512 + lane * 8;
  const ushort_t* gb1 = Bp + ((size_t)(n16b + 4 + wave) * NKB) * 512 + lane * 8;
  const int ldb0 = 1024 + wave * 512 + lane * 8;
  const int ldb1 = 1024 + (4 + wave) * 512 + lane * 8;

  // x read (lane-const byte offset): row = wm*32 + mf*16 + m, wants global
  // i-pair ko -> chunk (ko>>1)^((m>>2)&1), pair (ko&1). mf adds 512 B.
  const int xoff = wm * 1024 + m * 32 +
                   ((((ko >> 1) ^ ((m >> 2) & 1))) << 4) + (ko & 1) * 8;

  f32x4 acc[2][4];
  const f32x4 zero = {0.0f, 0.0f, 0.0f, 0.0f};
#pragma unroll
  for (int mf = 0; mf < 2; ++mf)
#pragma unroll
    for (int nf = 0; nf < 4; ++nf) acc[mf][nf] = zero;

#define WAITBAR(N) \
  asm volatile("s_waitcnt vmcnt(" #N ")\n\ts_barrier" ::: "memory")

// class X (waves 0,1): x-half + 2 B units at literal unit offset REL
#define STAGE_X(bb, rel)                                                \
  do {                                                                  \
    load_lds16(gx  + (rel) * 16,  &lds[bb][ldx]);                       \
    load_lds16(gb0 + (rel) * 512, &lds[bb][ldb0]);                      \
    load_lds16(gb1 + (rel) * 512, &lds[bb][ldb1]);                      \
  } while (0)

// class Y (waves 2,3): 2 B units only
#define STAGE_Y(bb, rel)                                                \
  do {                                                                  \
    load_lds16(gb0 + (rel) * 512, &lds[bb][ldb0]);                      \
    load_lds16(gb1 + (rel) * 512, &lds[bb][ldb1]);                      \
  } while (0)

// powers + pack: v_cvt_pk_bf16_f32 (RNE, same rounding as f2bf)
#define PACKA(dst, xp)                                                  \
  do {                                                                  \
    const f32x2 p1 = (xp);                                              \
    const f32x2 p2 = p1 * p1;                                           \
    const f32x2 p3 = p2 * p1;                                           \
    const f32x2 p4 = p2 * p2;                                           \
    union { bf16x8 v; unsigned int u[4]; } r_;                          \
    asm("v_cvt_pk_bf16_f32 %0, %1, %2" : "=v"(r_.u[0]) : "v"(p1[0]), "v"(p2[0])); \
    asm("v_cvt_pk_bf16_f32 %0, %1, %2" : "=v"(r_.u[1]) : "v"(p3[0]), "v"(p4[0])); \
    asm("v_cvt_pk_bf16_f32 %0, %1, %2" : "=v"(r_.u[2]) : "v"(p1[1]), "v"(p2[1])); \
    asm("v_cvt_pk_bf16_f32 %0, %1, %2" : "=v"(r_.u[3]) : "v"(p3[1]), "v"(p4[1])); \
    dst = r_.v;                                                         \
  } while (0)

#define COMPUTE(bb)                                                     \
  do {                                                                  \
    const char* xu = (const char*)&lds[bb][0];                          \
    const f32x2 q0 = *(const f32x2*)(xu + xoff);                        \
    const f32x2 q1 = *(const f32x2*)(xu + xoff + 512);                  \
    bf16x8 a[2], b[4];                                                  \
    PACKA(a[0], q0);                                                    \
    PACKA(a[1], q1);                                                    \
    _Pragma("unroll")                                                   \
    for (int nf = 0; nf < 4; ++nf)                                      \
      b[nf] = *(const bf16x8*)&lds[bb][1024 + (wn * 4 + nf) * 512 + lane * 8]; \
    _Pragma("unroll")                                                   \
    for (int mf = 0; mf < 2; ++mf)                                      \
      _Pragma("unroll")                                                 \
      for (int nf = 0; nf < 4; ++nf)                                    \
        acc[mf][nf] = __builtin_amdgcn_mfma_f32_16x16x32_bf16(          \
            a[mf], b[nf], acc[mf][nf], 0, 0, 0);                        \
  } while (0)

  if (wave < 2) {
    // ---- class X: proven ledger (3 loads/iter) ----
    STAGE_X(0, 0);
    STAGE_X(1, 1);
    STAGE_X(2, 2);
    gx  += 4 * 16;                        // rebase: rel 0 == k-block 4
    gb0 += 4 * 512;
    gb1 += 4 * 512;
    for (int base = 0; base < 124; base += 4) {
      WAITBAR(6); STAGE_X(3, -1); COMPUTE(0);   // stage base+3
      WAITBAR(6); STAGE_X(0,  0); COMPUTE(1);   // stage base+4
      WAITBAR(6); STAGE_X(1,  1); COMPUTE(2);   // stage base+5
      WAITBAR(6); STAGE_X(2,  2); COMPUTE(3);   // stage base+6
      gx  += 4 * 16;
      gb0 += 4 * 512;
      gb1 += 4 * 512;
    }
    WAITBAR(6); STAGE_X(3, -1); COMPUTE(0);     // it=124, stage 127
    WAITBAR(6); COMPUTE(1);
    WAITBAR(3); COMPUTE(2);
    WAITBAR(0); COMPUTE(3);
  } else {
    // ---- class Y: same structure, 2 loads/iter, 2-stages-in-flight ----
    STAGE_Y(0, 0);
    STAGE_Y(1, 1);
    STAGE_Y(2, 2);
    gb0 += 4 * 512;
    gb1 += 4 * 512;
    for (int base = 0; base < 124; base += 4) {
      WAITBAR(4); STAGE_Y(3, -1); COMPUTE(0);
      WAITBAR(4); STAGE_Y(0,  0); COMPUTE(1);
      WAITBAR(4); STAGE_Y(1,  1); COMPUTE(2);
      WAITBAR(4); STAGE_Y(2,  2); COMPUTE(3);
      gb0 += 4 * 512;
      gb1 += 4 * 512;
    }
    WAITBAR(4); STAGE_Y(3, -1); COMPUTE(0);     // it=124, stage 127
    WAITBAR(4); COMPUTE(1);
    WAITBAR(2); COMPUTE(2);
    WAITBAR(0); COMPUTE(3);
  }
#undef STAGE_X
#undef STAGE_Y
#undef COMPUTE
#undef PACKA
#undef WAITBAR

  // epilogue: C/D map: col = lane&15, row = (lane>>4)*4 + reg
  const int crow0 = m16b * 16 + wm * 32 + (lane >> 4) * 4;
  const int ccol0 = n16b * 16 + wn * 64 + m;
#pragma unroll
  for (int nf = 0; nf < 4; ++nf) {
    const int col = ccol0 + nf * 16;
    const float bv = b2[col];
#pragma unroll
    for (int mf = 0; mf < 2; ++mf) {
#pragma unroll
      for (int r = 0; r < 4; ++r) {
        const int row = crow0 + mf * 16 + r;
        C[(size_t)row * U_DIM + col] = gelu_exact(acc[mf][nf][r] + bv);
      }
    }
  }
}

// ---------------- fallback (ws too small): fp32, no workspace ----------------
__global__ void fallback_kernel(const float* __restrict__ x, const float* __restrict__ W,
                                const float* __restrict__ bias, float* __restrict__ out) {
  int j  = blockIdx.x * 256 + threadIdx.x;
  int b0 = blockIdx.y * 16;
  float acc[16];
#pragma unroll
  for (int t = 0; t < 16; ++t) acc[t] = 0.0f;
  for (int i = 0; i < D_DIM; ++i) {
    const float* wr = W + (size_t)i * 5 * U_DIM + j;
    float w0 = wr[0 * U_DIM], w1 = wr[1 * U_DIM], w2 = wr[2 * U_DIM];
    float w3 = wr[3 * U_DIM], w4 = wr[4 * U_DIM];
#pragma unroll
    for (int t = 0; t < 16; ++t) {
      float xv = x[(size_t)(b0 + t) * D_DIM + i];
      float x2 = xv * xv;
      acc[t] += w0 + xv * w1 + x2 * w2 + x2 * xv * w3 + x2 * x2 * w4;
    }
  }
  float bv = bias[j];
#pragma unroll
  for (int t = 0; t < 16; ++t)
    out[(size_t)(b0 + t) * U_DIM + j] = gelu_exact(acc[t] + bv);
}

extern "C" void kernel_launch(void* const* d_in, const int* in_sizes, int n_in,
                              void* d_out, int out_size, void* d_ws, size_t ws_size,
                              hipStream_t stream) {
  const float* x    = (const float*)d_in[0];   // (4096, 1024)
  const float* W    = (const float*)d_in[1];   // (1024, 5, 1024), row r = i*5+k
  const float* bias = (const float*)d_in[2];   // (1024,)
  float* out = (float*)d_out;                  // (4096, 1024) fp32

  const size_t szB = (size_t)U_DIM * 4096 * sizeof(ushort_t);    // 8.39 MB
  const size_t szF = (size_t)32 * U_DIM * sizeof(float);         //  128 KB
  const size_t szb = (size_t)U_DIM * sizeof(float);              //    4 KB

  if (ws_size >= szB + szF + szb) {
    ushort_t* Bp   = (ushort_t*)d_ws;
    float*    f32p = (float*)((char*)d_ws + szB);
    float*    b2   = (float*)((char*)d_ws + szB + szF);
    w_pack_kernel<<<dim3(2048), 256, 0, stream>>>(W, Bp, f32p);
    fold_final_kernel<<<dim3(U_DIM / 256), 256, 0, stream>>>(f32p, bias, b2);
    gemm_kernel<<<dim3(U_DIM / 128, B_DIM / 64), 256, 0, stream>>>(x, Bp, b2, out);
  } else {
    fallback_kernel<<<dim3(U_DIM / 256, B_DIM / 16), 256, 0, stream>>>(x, W, bias, out);
  }
}